// Round 4
// baseline (111.630 us; speedup 1.0000x reference)
//
#include <hip/hip_runtime.h>
#include <math.h>

#define Bv 4
#define Nv 512
#define Dv 128
#define BND (Bv*Nv*Dv)      // 262144
#define NN  (Nv*Nv)         // 262144
#define EPSv 1e-9f

typedef float f4 __attribute__((ext_vector_type(4)));
typedef float f2 __attribute__((ext_vector_type(2)));

__device__ __forceinline__ f2 relu2(f2 z) {
#if __has_builtin(__builtin_elementwise_max)
    return __builtin_elementwise_max(z, (f2)0.0f);
#else
    z.x = fmaxf(z.x, 0.0f); z.y = fmaxf(z.y, 0.0f); return z;
#endif
}

// -------------------------------------------------------------------------
// k_prep R8: same phase structure as R5/R7 but issue-slot-optimized:
//  - phase A: f2 loads of UN/EL, f2 stores of A (4 copies), same reduce.
//  - phase B/C: thread = (1 row rw = t>>6, col-pair c0 = 2*(t&63)).
//    All weight loads become f2 (b64, 512B/wave coalesced); all fma become
//    packed (acc f2 += splat(es/pr scalar) * w2) -> v_pk_fma_f32 via ISel
//    (no inline asm: R6 lesson). es/pr scalar is wave-uniform (rw = wave id)
//    -> LDS broadcast, conflict-free.
//    Slots/thread: B 512->384, C 1024->640 (-33%).
// Grid 512 x 256 thr -> 2 blocks/CU unchanged.
// -------------------------------------------------------------------------
__global__ __launch_bounds__(256) void k_prep(
    const float* __restrict__ ES, const float* __restrict__ Wp,
    const float* __restrict__ bp, const float* __restrict__ W1,
    const float* __restrict__ b1, const float* __restrict__ EL,
    const float* __restrict__ UN,
    float* __restrict__ s_out, float* __restrict__ t_out,
    float* __restrict__ A_out)
{
    __shared__ float es[4][Dv];
    __shared__ float pr[4][Dv];
    __shared__ float sred[4];
    const int bi = blockIdx.x;        // 0..511
    const int t  = threadIdx.x;

    // ---- phase A: softmax((EL+gumbel)/TAU) for row bi, broadcast to 4 b's
    {
        const int row  = bi;
        const int col0 = 2*t;                       // 0..510
        const f2 u  = *(const f2*)(UN + row*Nv + col0);
        const f2 el = *(const f2*)(EL + row*Nv + col0);
        const float g0 = -__logf(-__logf(u.x + EPSv) + EPSv);
        const float g1 = -__logf(-__logf(u.y + EPSv) + EPSv);
        const float z0 = (el.x + g0) * 2.0f;        // 1/TAU = 2
        const float z1 = (el.y + g1) * 2.0f;

        float m = fmaxf(z0, z1);
        #pragma unroll
        for (int off = 32; off >= 1; off >>= 1)
            m = fmaxf(m, __shfl_xor(m, off, 64));
        if ((t & 63) == 0) sred[t >> 6] = m;
        __syncthreads();
        m = fmaxf(fmaxf(sred[0], sred[1]), fmaxf(sred[2], sred[3]));

        const float e0 = __expf(z0 - m);
        const float e1 = __expf(z1 - m);
        float ssum = e0 + e1;
        #pragma unroll
        for (int off = 32; off >= 1; off >>= 1)
            ssum += __shfl_xor(ssum, off, 64);
        __syncthreads();
        if ((t & 63) == 0) sred[t >> 6] = ssum;
        __syncthreads();
        const float inv = 1.0f / (sred[0] + sred[1] + sred[2] + sred[3]);
        f2 a; a.x = e0 * inv; a.y = e1 * inv;
        #pragma unroll
        for (int bb = 0; bb < Bv; ++bb)
            *(f2*)(A_out + bb*NN + row*Nv + col0) = a;
    }

    // ---- phase B: proj for rows bi*4 .. bi*4+3 (thread: 1 row, 2 cols)
    const int row0 = bi * 4;
    const int rw = t >> 6;            // 0..3  (wave-uniform row)
    const int c0 = 2*(t & 63);        // 0,2,..,126

    for (int idx = t; idx < 4*Dv; idx += 256)
        es[idx >> 7][idx & 127] = ES[(row0 + (idx >> 7))*Dv + (idx & 127)];
    __syncthreads();

    {
        f2 acc = *(const f2*)(bp + c0);
        #pragma unroll 8
        for (int k = 0; k < Dv; ++k) {
            const f2 w = *(const f2*)(Wp + k*Dv + c0);   // b64 coalesced
            acc += (f2)(es[rw][k]) * w;                  // pk_fma, LDS bcast
        }
        *(f2*)(&pr[rw][c0]) = acc;
    }
    __syncthreads();

    // ---- phase C: s' = proj@W1_src + b1, t = proj@W1_tgt (1 row, 2 cols)
    f2 sacc = *(const f2*)(b1 + c0);
    f2 tacc = (f2)0.0f;
    #pragma unroll 8
    for (int k = 0; k < Dv; ++k) {
        const f2 ws_ = *(const f2*)(W1 + k*Dv + c0);         // b64
        const f2 wt_ = *(const f2*)(W1 + (Dv + k)*Dv + c0);  // b64
        const float p = pr[rw][k];                           // bcast
        sacc += (f2)p * ws_;
        tacc += (f2)p * wt_;
    }
    const int ra = (row0 + rw)*Dv + c0;
    *(f2*)(s_out + ra) = sacc;
    *(f2*)(t_out + ra) = tacc;
}

// -------------------------------------------------------------------------
// k_main (UNCHANGED from R7, known-good): f2-wide, 1024 thr/block,
// grid (64,4), 4 waves/SIMD, 1-iter-ahead sv prefetch, C-level f2 math
// (ISel forms v_pk_add/fma_f32). LDS 52 KB.
// -------------------------------------------------------------------------
__global__ __launch_bounds__(1024, 4) void k_main(
    const float* __restrict__ s_buf, const float* __restrict__ t_buf,
    const float* __restrict__ A0,    const float* __restrict__ ES,
    const float* __restrict__ W2,    const float* __restrict__ b2,
    float* __restrict__ out)
{
    __shared__ float A_lds[8][Nv];     // 16 KB
    __shared__ f2    part[16][8][64];  // 32 KB [jg][i][dh]
    __shared__ float hsum[8][Dv];      // 4 KB
    const int i0 = blockIdx.x * 8;
    const int b  = blockIdx.y;
    const int t  = threadIdx.x;
    const int dh = t & 63;             // d = dh*2, dh*2+1
    const int jg = t >> 6;             // 0..15 -> j in [jg*32, jg*32+32)

    // stage A rows i0..i0+7 (b-independent copy 0), coalesced f4, 1/thread
    {
        const f4* __restrict__ src = (const f4*)(A0 + i0*Nv);
        f4* dst = (f4*)(&A_lds[0][0]);
        dst[t] = src[t];
    }

    f2 tv[8];
    #pragma unroll
    for (int r = 0; r < 8; ++r)
        tv[r] = *(const f2*)(t_buf + (b*Nv + i0 + r)*Dv + dh*2);

    f2 acc[8];
    #pragma unroll
    for (int r = 0; r < 8; ++r) acc[r] = (f2)0.0f;

    __syncthreads();                   // A_lds ready

    const float* __restrict__ sb = s_buf + (size_t)b*Nv*Dv + dh*2;
    const int j0 = jg * 32;

    // prefetch first j4 quad (b64 loads)
    f2 svn0 = *(const f2*)(sb + (j0+0)*Dv);
    f2 svn1 = *(const f2*)(sb + (j0+1)*Dv);
    f2 svn2 = *(const f2*)(sb + (j0+2)*Dv);
    f2 svn3 = *(const f2*)(sb + (j0+3)*Dv);

    #pragma unroll
    for (int jj = 0; jj < 32; jj += 4) {
        const int j4 = j0 + jj;
        const f2 sv0 = svn0, sv1 = svn1, sv2 = svn2, sv3 = svn3;
        if (jj < 28) {                 // compile-time under full unroll
            svn0 = *(const f2*)(sb + (j4+4)*Dv);
            svn1 = *(const f2*)(sb + (j4+5)*Dv);
            svn2 = *(const f2*)(sb + (j4+6)*Dv);
            svn3 = *(const f2*)(sb + (j4+7)*Dv);
        }
        f4 a[8];
        #pragma unroll
        for (int r = 0; r < 8; ++r)
            a[r] = *(const f4*)(&A_lds[r][j4]);   // wave-broadcast, free
        #pragma unroll
        for (int r = 0; r < 8; ++r) {
            acc[r] += relu2(sv0 + tv[r]) * (f2)(a[r][0]);
            acc[r] += relu2(sv1 + tv[r]) * (f2)(a[r][1]);
            acc[r] += relu2(sv2 + tv[r]) * (f2)(a[r][2]);
            acc[r] += relu2(sv3 + tv[r]) * (f2)(a[r][3]);
        }
    }

    // jg-partials -> LDS, reduce 16-way
    #pragma unroll
    for (int r = 0; r < 8; ++r) part[jg][r][dh] = acc[r];
    __syncthreads();
    if (t < 512) {
        const int ri = t >> 6;         // 0..7
        f2 s = part[0][ri][dh];
        #pragma unroll
        for (int g = 1; g < 16; ++g) s += part[g][ri][dh];
        *(f2*)(&hsum[ri][dh*2]) = s;
    }
    __syncthreads();

    // epilogue: out = ES + hsum@W2 + b2; thread = (1 row rr, 1 col c)
    const int c  = t & 127;
    const int rr = t >> 7;             // 0..7
    float o = b2[c];
    #pragma unroll 8
    for (int k4 = 0; k4 < Dv; k4 += 4) {
        const f4 h = *(const f4*)(&hsum[rr][k4]);  // b128 wave-broadcast
        o = fmaf(h[0], W2[(k4+0)*Dv + c], o);
        o = fmaf(h[1], W2[(k4+1)*Dv + c], o);
        o = fmaf(h[2], W2[(k4+2)*Dv + c], o);
        o = fmaf(h[3], W2[(k4+3)*Dv + c], o);
    }
    const int ro = (b*Nv + i0 + rr)*Dv + c;
    out[ro] = ES[ro] + o;
}

extern "C" void kernel_launch(void* const* d_in, const int* in_sizes, int n_in,
                              void* d_out, int out_size, void* d_ws, size_t ws_size,
                              hipStream_t stream) {
    (void)in_sizes; (void)n_in; (void)out_size; (void)ws_size;
    const float* ES = (const float*)d_in[0];
    const float* Wp = (const float*)d_in[1];
    const float* bp = (const float*)d_in[2];
    const float* EL = (const float*)d_in[3];
    const float* W1 = (const float*)d_in[4];
    const float* b1 = (const float*)d_in[5];
    const float* W2 = (const float*)d_in[6];
    const float* b2 = (const float*)d_in[7];
    const float* UN = (const float*)d_in[8];

    float* out   = (float*)d_out;
    float* A_out = out + BND;            // A broadcast region: B*N*N floats

    float* s_buf = (float*)d_ws;         // s' = proj@W1_src + b1  (B*N*D)
    float* t_buf = s_buf + BND;          // t  = proj@W1_tgt       (B*N*D)

    k_prep<<<512, 256, 0, stream>>>(ES, Wp, bp, W1, b1, EL, UN,
                                    s_buf, t_buf, A_out);
    k_main<<<dim3(Nv/8, Bv), 1024, 0, stream>>>(s_buf, t_buf, A_out, ES, W2, b2,
                                                out);
}

// Round 5
// 100.158 us; speedup vs baseline: 1.1145x; 1.1145x over previous
//
#include <hip/hip_runtime.h>
#include <math.h>

#define Bv 4
#define Nv 512
#define Dv 128
#define BND (Bv*Nv*Dv)      // 262144
#define NN  (Nv*Nv)         // 262144
#define EPSv 1e-9f

typedef float f4 __attribute__((ext_vector_type(4)));
typedef float f2 __attribute__((ext_vector_type(2)));

__device__ __forceinline__ f2 relu2(f2 z) {
#if __has_builtin(__builtin_elementwise_max)
    return __builtin_elementwise_max(z, (f2)0.0f);
#else
    z.x = fmaxf(z.x, 0.0f); z.y = fmaxf(z.y, 0.0f); return z;
#endif
}

// -------------------------------------------------------------------------
// k_prep R9 = R7-exact phases A and B (known-good, 99.1us run), with ONE
// surgical change in phase C: split by OUTPUT-TYPE instead of by row.
//   R7: thread (c, rg) computed s AND t for 2 rows -> each wave loads BOTH
//       W1src and W1tgt streams (512 B/wave/k). Phase C = 128 MB of L2.
//   R9: waves 0-1 (rg=0) compute s for all 4 rows off W1src only; waves
//       2-3 compute t off W1tgt only -> 256 B/wave/k, amortized over 4
//       rows. Phase C traffic halves (128->64 MB); 4 indep fma chains.
//   fma order per output identical to R7 -> bit-identical results.
// k_prep is L2-weight-stream-bound (R8 post-mortem), NOT issue-bound.
// -------------------------------------------------------------------------
__global__ __launch_bounds__(256) void k_prep(
    const float* __restrict__ ES, const float* __restrict__ Wp,
    const float* __restrict__ bp, const float* __restrict__ W1,
    const float* __restrict__ b1, const float* __restrict__ EL,
    const float* __restrict__ UN,
    float* __restrict__ s_out, float* __restrict__ t_out,
    float* __restrict__ A_out)
{
    __shared__ float es[4][Dv];
    __shared__ float pr[4][Dv];
    __shared__ float sred[4];
    const int bi = blockIdx.x;        // 0..511
    const int t  = threadIdx.x;

    // ---- phase A: softmax((EL+gumbel)/TAU) for row bi, broadcast to 4 b's
    {
        const int row = bi;
        const float u0 = UN[row*Nv + t];
        const float u1 = UN[row*Nv + t + 256];
        const float g0 = -__logf(-__logf(u0 + EPSv) + EPSv);
        const float g1 = -__logf(-__logf(u1 + EPSv) + EPSv);
        const float z0 = (EL[row*Nv + t]       + g0) * 2.0f;   // 1/TAU = 2
        const float z1 = (EL[row*Nv + t + 256] + g1) * 2.0f;

        float m = fmaxf(z0, z1);
        #pragma unroll
        for (int off = 32; off >= 1; off >>= 1)
            m = fmaxf(m, __shfl_xor(m, off, 64));
        if ((t & 63) == 0) sred[t >> 6] = m;
        __syncthreads();
        m = fmaxf(fmaxf(sred[0], sred[1]), fmaxf(sred[2], sred[3]));

        const float e0 = __expf(z0 - m);
        const float e1 = __expf(z1 - m);
        float ssum = e0 + e1;
        #pragma unroll
        for (int off = 32; off >= 1; off >>= 1)
            ssum += __shfl_xor(ssum, off, 64);
        __syncthreads();
        if ((t & 63) == 0) sred[t >> 6] = ssum;
        __syncthreads();
        const float inv = 1.0f / (sred[0] + sred[1] + sred[2] + sred[3]);
        const float a0 = e0 * inv;
        const float a1 = e1 * inv;
        #pragma unroll
        for (int bb = 0; bb < Bv; ++bb) {
            A_out[bb*NN + row*Nv + t]       = a0;
            A_out[bb*NN + row*Nv + t + 256] = a1;
        }
    }

    // ---- phase B: proj for rows bi*4 .. bi*4+3 (R7-exact)
    const int row0 = bi * 4;
    const int c  = t & 127;
    const int rg = t >> 7;            // 0..1

    for (int idx = t; idx < 4*Dv; idx += 256)
        es[idx >> 7][idx & 127] = ES[(row0 + (idx >> 7))*Dv + (idx & 127)];
    __syncthreads();

    {
        float acc[2];
        const float bpc = bp[c];
        acc[0] = bpc; acc[1] = bpc;
        #pragma unroll 8
        for (int k = 0; k < Dv; ++k) {
            const float w = Wp[k*Dv + c];
            acc[0] = fmaf(es[rg*2][k],   w, acc[0]);
            acc[1] = fmaf(es[rg*2+1][k], w, acc[1]);
        }
        pr[rg*2][c]   = acc[0];
        pr[rg*2+1][c] = acc[1];
    }
    __syncthreads();

    // ---- phase C (R9): rg=0 waves -> s for rows 0..3 (W1src stream);
    //                    rg=1 waves -> t for rows 0..3 (W1tgt stream).
    // One 256B weight load per wave per k, 4 independent fma chains.
    {
        const float* __restrict__ Wsel = W1 + (rg ? (size_t)Dv*Dv : 0);
        const float seed = rg ? 0.0f : b1[c];
        float a0 = seed, a1 = seed, a2 = seed, a3 = seed;
        #pragma unroll 8
        for (int k = 0; k < Dv; ++k) {
            const float w = Wsel[k*Dv + c];      // 256B/wave, single stream
            const float p0 = pr[0][k];           // wave-uniform broadcasts
            const float p1 = pr[1][k];
            const float p2 = pr[2][k];
            const float p3 = pr[3][k];
            a0 = fmaf(p0, w, a0);
            a1 = fmaf(p1, w, a1);
            a2 = fmaf(p2, w, a2);
            a3 = fmaf(p3, w, a3);
        }
        float* __restrict__ obuf = rg ? t_out : s_out;
        const int rb = row0*Dv + c;
        obuf[rb]        = a0;
        obuf[rb +   Dv] = a1;
        obuf[rb + 2*Dv] = a2;
        obuf[rb + 3*Dv] = a3;
    }
}

// -------------------------------------------------------------------------
// k_main (UNCHANGED from R7, known-good): f2-wide, 1024 thr/block,
// grid (64,4), 4 waves/SIMD, 1-iter-ahead sv prefetch, C-level f2 math
// (ISel forms v_pk_add/fma_f32). LDS 52 KB.
// -------------------------------------------------------------------------
__global__ __launch_bounds__(1024, 4) void k_main(
    const float* __restrict__ s_buf, const float* __restrict__ t_buf,
    const float* __restrict__ A0,    const float* __restrict__ ES,
    const float* __restrict__ W2,    const float* __restrict__ b2,
    float* __restrict__ out)
{
    __shared__ float A_lds[8][Nv];     // 16 KB
    __shared__ f2    part[16][8][64];  // 32 KB [jg][i][dh]
    __shared__ float hsum[8][Dv];      // 4 KB
    const int i0 = blockIdx.x * 8;
    const int b  = blockIdx.y;
    const int t  = threadIdx.x;
    const int dh = t & 63;             // d = dh*2, dh*2+1
    const int jg = t >> 6;             // 0..15 -> j in [jg*32, jg*32+32)

    // stage A rows i0..i0+7 (b-independent copy 0), coalesced f4, 1/thread
    {
        const f4* __restrict__ src = (const f4*)(A0 + i0*Nv);
        f4* dst = (f4*)(&A_lds[0][0]);
        dst[t] = src[t];
    }

    f2 tv[8];
    #pragma unroll
    for (int r = 0; r < 8; ++r)
        tv[r] = *(const f2*)(t_buf + (b*Nv + i0 + r)*Dv + dh*2);

    f2 acc[8];
    #pragma unroll
    for (int r = 0; r < 8; ++r) acc[r] = (f2)0.0f;

    __syncthreads();                   // A_lds ready

    const float* __restrict__ sb = s_buf + (size_t)b*Nv*Dv + dh*2;
    const int j0 = jg * 32;

    // prefetch first j4 quad (b64 loads)
    f2 svn0 = *(const f2*)(sb + (j0+0)*Dv);
    f2 svn1 = *(const f2*)(sb + (j0+1)*Dv);
    f2 svn2 = *(const f2*)(sb + (j0+2)*Dv);
    f2 svn3 = *(const f2*)(sb + (j0+3)*Dv);

    #pragma unroll
    for (int jj = 0; jj < 32; jj += 4) {
        const int j4 = j0 + jj;
        const f2 sv0 = svn0, sv1 = svn1, sv2 = svn2, sv3 = svn3;
        if (jj < 28) {                 // compile-time under full unroll
            svn0 = *(const f2*)(sb + (j4+4)*Dv);
            svn1 = *(const f2*)(sb + (j4+5)*Dv);
            svn2 = *(const f2*)(sb + (j4+6)*Dv);
            svn3 = *(const f2*)(sb + (j4+7)*Dv);
        }
        f4 a[8];
        #pragma unroll
        for (int r = 0; r < 8; ++r)
            a[r] = *(const f4*)(&A_lds[r][j4]);   // wave-broadcast, free
        #pragma unroll
        for (int r = 0; r < 8; ++r) {
            acc[r] += relu2(sv0 + tv[r]) * (f2)(a[r][0]);
            acc[r] += relu2(sv1 + tv[r]) * (f2)(a[r][1]);
            acc[r] += relu2(sv2 + tv[r]) * (f2)(a[r][2]);
            acc[r] += relu2(sv3 + tv[r]) * (f2)(a[r][3]);
        }
    }

    // jg-partials -> LDS, reduce 16-way
    #pragma unroll
    for (int r = 0; r < 8; ++r) part[jg][r][dh] = acc[r];
    __syncthreads();
    if (t < 512) {
        const int ri = t >> 6;         // 0..7
        f2 s = part[0][ri][dh];
        #pragma unroll
        for (int g = 1; g < 16; ++g) s += part[g][ri][dh];
        *(f2*)(&hsum[ri][dh*2]) = s;
    }
    __syncthreads();

    // epilogue: out = ES + hsum@W2 + b2; thread = (1 row rr, 1 col c)
    const int c  = t & 127;
    const int rr = t >> 7;             // 0..7
    float o = b2[c];
    #pragma unroll 8
    for (int k4 = 0; k4 < Dv; k4 += 4) {
        const f4 h = *(const f4*)(&hsum[rr][k4]);  // b128 wave-broadcast
        o = fmaf(h[0], W2[(k4+0)*Dv + c], o);
        o = fmaf(h[1], W2[(k4+1)*Dv + c], o);
        o = fmaf(h[2], W2[(k4+2)*Dv + c], o);
        o = fmaf(h[3], W2[(k4+3)*Dv + c], o);
    }
    const int ro = (b*Nv + i0 + rr)*Dv + c;
    out[ro] = ES[ro] + o;
}

extern "C" void kernel_launch(void* const* d_in, const int* in_sizes, int n_in,
                              void* d_out, int out_size, void* d_ws, size_t ws_size,
                              hipStream_t stream) {
    (void)in_sizes; (void)n_in; (void)out_size; (void)ws_size;
    const float* ES = (const float*)d_in[0];
    const float* Wp = (const float*)d_in[1];
    const float* bp = (const float*)d_in[2];
    const float* EL = (const float*)d_in[3];
    const float* W1 = (const float*)d_in[4];
    const float* b1 = (const float*)d_in[5];
    const float* W2 = (const float*)d_in[6];
    const float* b2 = (const float*)d_in[7];
    const float* UN = (const float*)d_in[8];

    float* out   = (float*)d_out;
    float* A_out = out + BND;            // A broadcast region: B*N*N floats

    float* s_buf = (float*)d_ws;         // s' = proj@W1_src + b1  (B*N*D)
    float* t_buf = s_buf + BND;          // t  = proj@W1_tgt       (B*N*D)

    k_prep<<<512, 256, 0, stream>>>(ES, Wp, bp, W1, b1, EL, UN,
                                    s_buf, t_buf, A_out);
    k_main<<<dim3(Nv/8, Bv), 1024, 0, stream>>>(s_buf, t_buf, A_out, ES, W2, b2,
                                                out);
}